// Round 20
// baseline (240.168 us; speedup 1.0000x reference)
//
#include <hip/hip_runtime.h>

#define NB 8
#define NS 1024
#define ND 1024
#define NH 16
#define NHD 64

typedef __attribute__((ext_vector_type(8))) short bf16x8;
typedef __attribute__((ext_vector_type(4))) float f32x4;
typedef __attribute__((ext_vector_type(4))) unsigned int u32x4;

#define GLOAD_LDS16(g, l) __builtin_amdgcn_global_load_lds(                    \
    (const __attribute__((address_space(1))) void*)(g),                        \
    (__attribute__((address_space(3))) void*)(l), 16, 0, 0)

static __device__ __forceinline__ unsigned short f2bf(float f) {
    unsigned int u = __builtin_bit_cast(unsigned int, f);
    unsigned int r = u + 0x7fffu + ((u >> 16) & 1u);
    return (unsigned short)(r >> 16);
}

static __device__ __forceinline__ unsigned int cvtpk(float lo, float hi) {
    unsigned int r;
    asm("v_cvt_pk_bf16_f32 %0, %1, %2" : "=v"(r) : "v"(lo), "v"(hi));
    return r;
}

// load float from LDS table by BYTE offset (rel codes are pre-shifted <<2)
static __device__ __forceinline__ float ldre(const float* t, unsigned int byteoff) {
    return *reinterpret_cast<const float*>(reinterpret_cast<const char*>(t) + byteoff);
}

// ---------------- fp32 -> bf16 convert ----------------
__global__ void cvt_f32_bf16(const float* __restrict__ in, unsigned short* __restrict__ out, int n) {
    int i = (blockIdx.x * blockDim.x + threadIdx.x) * 4;
    if (i >= n) return;
    float4 v = *reinterpret_cast<const float4*>(in + i);
    ushort4 o;
    o.x = f2bf(v.x); o.y = f2bf(v.y); o.z = f2bf(v.z); o.w = f2bf(v.w);
    *reinterpret_cast<ushort4*>(out + i) = o;
}

// 3 weight matrices in one launch (grid.y selects source)
__global__ void cvt_w3(const float* __restrict__ Wq, const float* __restrict__ Wk,
                       const float* __restrict__ Wv, unsigned short* __restrict__ out) {
    const float* src = (blockIdx.y == 0) ? Wq : (blockIdx.y == 1) ? Wk : Wv;
    int i = (blockIdx.x * blockDim.x + threadIdx.x) * 4;
    float4 v = *reinterpret_cast<const float4*>(src + i);
    ushort4 o;
    o.x = f2bf(v.x); o.y = f2bf(v.y); o.z = f2bf(v.z); o.w = f2bf(v.w);
    *reinterpret_cast<ushort4*>(out + (size_t)blockIdx.y * (ND * ND) + i) = o;
}

// rel int32 -> packed int8, PRE-SHIFTED <<2 (byte value = LDS float byte-offset).
__global__ void pack_rel8(const int* __restrict__ rel, unsigned int* __restrict__ out) {
    int i = blockIdx.x * blockDim.x + threadIdx.x;
    int4 v = reinterpret_cast<const int4*>(rel)[i];
    out[i] = ((unsigned)v.x << 2) | ((unsigned)v.y << 10) |
             ((unsigned)v.z << 18) | ((unsigned)v.w << 26);
}

// ---------------- QKV projection GEMM (r17: LDS-bounce epilogue) ----------------
__global__ __launch_bounds__(256) void qkv_gemm(
    const unsigned short* __restrict__ A,
    const unsigned short* __restrict__ Wq, const unsigned short* __restrict__ Wk,
    const unsigned short* __restrict__ Wv,
    const float* __restrict__ bq, const float* __restrict__ bk, const float* __restrict__ bv,
    const float* __restrict__ mask,
    unsigned short* __restrict__ Qo, unsigned short* __restrict__ Ko, unsigned short* __restrict__ Vo)
{
    const int z = blockIdx.z;
    const unsigned short* W = (z == 0) ? Wq : (z == 1) ? Wk : Wv;
    const float* bias = (z == 0) ? bq : (z == 1) ? bk : bv;
    const int m0 = blockIdx.x * 128;
    const int n0 = blockIdx.y * 128;
    const float LOG2E = 1.4426950408889634f;
    const float QSCL = 0.125f * 1.4426950408889634f;

    __shared__ unsigned short S[2][128][64];   // As=S[0], Bs=S[1]; 32 KB total

    const int tid = threadIdx.x;
    const int lane = tid & 63;
    const int wave = tid >> 6;
    const int wm = wave >> 1, wn = wave & 1;
    const int g = lane >> 4, l15 = lane & 15;

    f32x4 acc[4][4] = {};

    const int crow = lane >> 3;                    // row within chunk 0..7
    const int gcol = ((lane & 7) ^ crow) * 8;      // pre-swizzled source col (elems)
    const int kofs = g * 8;

    for (int kb = 0; kb < ND; kb += 64) {
#pragma unroll
        for (int cc = 0; cc < 4; ++cc) {
            int ch = wave * 4 + cc;                // 16 chunks each
            GLOAD_LDS16(&A[(size_t)(m0 + ch * 8 + crow) * ND + kb + gcol], &S[0][ch * 8][0]);
            GLOAD_LDS16(&W[(size_t)(n0 + ch * 8 + crow) * ND + kb + gcol], &S[1][ch * 8][0]);
        }
        __syncthreads();
#pragma unroll
        for (int kk = 0; kk < 2; ++kk) {
            const int colx = (kk * 32 + kofs) ^ ((lane & 7) * 8);
            bf16x8 af[4], bfr[4];
#pragma unroll
            for (int i = 0; i < 4; ++i) {
                af[i]  = *reinterpret_cast<const bf16x8*>(&S[0][wm * 64 + i * 16 + l15][colx]);
                bfr[i] = *reinterpret_cast<const bf16x8*>(&S[1][wn * 64 + i * 16 + l15][colx]);
            }
#pragma unroll
            for (int mi = 0; mi < 4; ++mi)
#pragma unroll
                for (int ni = 0; ni < 4; ++ni)
                    acc[mi][ni] = __builtin_amdgcn_mfma_f32_16x16x32_bf16(af[mi], bfr[ni], acc[mi][ni], 0, 0, 0);
        }
        __syncthreads();
    }

    // -------- LDS-bounce epilogue: per-wave 8 KB slice of S --------
    __syncthreads();   // all waves done reading S
    char* L = reinterpret_cast<char*>(&S[0][0][0]) + wave * 8192;
    const int rrow = lane >> 3, cb = lane & 7;

    if (z == 2) {
#pragma unroll
        for (int ni = 0; ni < 4; ++ni) {
            int n = n0 + wn * 64 + ni * 16 + l15;
            int nl = ni * 16 + l15;
            float bv_ = bias[n];
#pragma unroll
            for (int mi = 0; mi < 4; ++mi) {
                int m = m0 + wm * 64 + mi * 16 + g * 4;
                int b = m >> 10, s = m & 1023;
                float4 mv = *reinterpret_cast<const float4*>(&mask[(size_t)b * NS + s]);
                unsigned int lo = cvtpk((acc[mi][ni][0] + bv_) * exp2f(mv.x * LOG2E),
                                        (acc[mi][ni][1] + bv_) * exp2f(mv.y * LOG2E));
                unsigned int hi = cvtpk((acc[mi][ni][2] + bv_) * exp2f(mv.z * LOG2E),
                                        (acc[mi][ni][3] + bv_) * exp2f(mv.w * LOG2E));
                int ml = mi * 16 + g * 4;
                int off = nl * 128 + (((ml >> 3) ^ (nl & 7)) * 16) + (ml & 7) * 2;
                *reinterpret_cast<uint2*>(L + off) = make_uint2(lo, hi);
            }
        }
#pragma unroll
        for (int p = 0; p < 8; ++p) {
            int nl = p * 8 + rrow;
            u32x4 v = *reinterpret_cast<const u32x4*>(L + nl * 128 + ((cb ^ (nl & 7)) * 16));
            int n = n0 + wn * 64 + nl;
            int h = n >> 6, hd = n & 63;
            int m = m0 + wm * 64 + cb * 8;
            int b = m >> 10, s = m & 1023;
            *reinterpret_cast<u32x4*>(&Vo[(((size_t)b * NH + h) * NHD + hd) * NS + s]) = v;
        }
    } else {
        unsigned short* O = (z == 0) ? Qo : Ko;
#pragma unroll
        for (int ni = 0; ni < 4; ++ni) {
            int n = n0 + wn * 64 + ni * 16 + l15;
            int nl = ni * 16 + l15;
            float bv_ = bias[n];
            int c16 = nl >> 3, bin = (nl & 7) * 2;
#pragma unroll
            for (int mi = 0; mi < 4; ++mi) {
#pragma unroll
                for (int r = 0; r < 4; ++r) {
                    int ml = mi * 16 + g * 4 + r;
                    float v = acc[mi][ni][r] + bv_;
                    if (z == 0) v *= QSCL;
                    int off = ml * 128 + ((c16 ^ (ml & 7)) * 16) + bin;
                    *reinterpret_cast<unsigned short*>(L + off) = f2bf(v);
                }
            }
        }
#pragma unroll
        for (int p = 0; p < 8; ++p) {
            int ml = p * 8 + rrow;
            u32x4 v = *reinterpret_cast<const u32x4*>(L + ml * 128 + ((cb ^ (ml & 7)) * 16));
            int m = m0 + wm * 64 + ml;
            int b = m >> 10, s = m & 1023;
            int n = n0 + wn * 64 + cb * 8;
            int h = n >> 6, hd = n & 63;
            *reinterpret_cast<u32x4*>(&O[(((size_t)b * NH + h) * NS + s) * NHD + hd]) = v;
        }
    }
}

// ---------------- flash attention: r17 structure, V read DIRECT from global ------
// flat grid 1024, block 512 (8 waves), 16 q-rows/wave. V^T is [b][h][hd][s], so
// the PV B-fragment is a contiguous per-lane 16B global load — no staging needed
// (m169: don't stage what caches fit). K/V per (b,h) is 256 KB, shared by the 8
// XCD-clustered q0-blocks (L2) and by the block's 8 phase-locked waves (L1).
// This removes 8 of 18 ds_read_b128 per wave-tile and halves the STAGE, at
// ~zero VGPR cost (must stay <= 64: the r19 q-tiling failure was the VGPR cliff).
__global__ __launch_bounds__(512) void flash_attn(
    const unsigned short* __restrict__ Q, const unsigned short* __restrict__ Kb,
    const unsigned short* __restrict__ Vt,
    const unsigned char* __restrict__ rel8, const float* __restrict__ rel_emb,
    const float* __restrict__ mask, float* __restrict__ out)
{
    const int id = blockIdx.x;
    const int b = id & 7;                 // XCD-clustered batch
    const int h = (id >> 3) & 15;
    const int q0 = (id >> 7) * 128;
    const int tid = threadIdx.x, lane = tid & 63, wave = tid >> 6;  // wave 0..7
    const int g = lane >> 4, l15 = lane & 15;

    __shared__ unsigned short Ks[2][64][64]; // [buf][perm-kv][hd], chunk-swizzled, 16 KB
    __shared__ unsigned short s_emask[NS];   // bf16 exp2(mask*log2e), 2 KB
    __shared__ float s_re2[8];               // rel_emb[.][h] * log2(e) - 4.0
    const float LOG2E = 1.4426950408889634f;
    if (tid < 7) s_re2[tid] = rel_emb[tid * NH + h] * LOG2E - 4.0f;

    const unsigned short* Qh = Q  + (((size_t)b * NH + h) * NS) * NHD;
    const unsigned short* Kh = Kb + (((size_t)b * NH + h) * NS) * NHD;
    const unsigned short* Vh = Vt + (((size_t)b * NH + h) * NHD) * NS;
    const int qg = q0 + wave * 16 + l15;                 // this lane's q-row
    const unsigned char* __restrict__ relrow = rel8 + (size_t)b * NS * NS + (size_t)qg * NS;
    const float* __restrict__ maskb = mask + (size_t)b * NS;

    bf16x8 qa[2];
    qa[0] = *reinterpret_cast<const bf16x8*>(&Qh[(size_t)qg * NHD + g * 8]);
    qa[1] = *reinterpret_cast<const bf16x8*>(&Qh[(size_t)qg * NHD + 32 + g * 8]);

    // per-lane V base: row = l15 (hd within 16-group), col slice = g*8
    const unsigned short* __restrict__ Vl = Vh + (size_t)l15 * NS + g * 8;

    f32x4 ctx[4] = {};
    f32x4 l_acc = {};
    float mofs = 0.f;            // running-max minus the folded base (4.0)
    bool everscaled = false;     // sticky, wave-uniform

    const int crow = lane >> 3;
    const int gcol = ((lane & 7) ^ crow) * 8;
    const int swz8 = (lane & 7) * 8;          // == (l15&7)*8

    // K row-permutation for staging (loop-invariant per lane):
    const int rho = wave * 8 + crow;
    const int kvperm = ((rho >> 5) << 5) + (((rho >> 2) & 3) << 3)
                     + (((rho >> 4) & 1) << 2) + (rho & 3);

#define STAGE(buf, kv)                                                                          \
    {                                                                                           \
        GLOAD_LDS16(&Kh[(size_t)((kv) + kvperm) * NHD + gcol], &Ks[buf][wave * 8][0]);          \
    }

    // packed rel codes for tile t0: kv = 8g..8g+7 and 32+8g..+7 -> two 8B chunks
#define LOADRM(S, t0)                                                                \
    {                                                                                \
        r##S##a = *reinterpret_cast<const uint2*>(&relrow[(t0) * 64 + 8 * g]);       \
        r##S##b = *reinterpret_cast<const uint2*>(&relrow[(t0) * 64 + 32 + 8 * g]);  \
    }

    uint2 rAa, rAb, rBa, rBb;

    STAGE(0, 0)
    LOADRM(A, 0)
    s_emask[tid] = f2bf(exp2f(maskb[tid] * LOG2E));
    s_emask[tid + 512] = f2bf(exp2f(maskb[tid + 512] * LOG2E));
    __syncthreads();

#define BODY(cur, S, SN, tc, tn)                                               \
  {                                                                            \
    if ((tn) < 16) {                                                           \
      STAGE(cur ^ 1, (tn) * 64)                                                \
      LOADRM(SN, tn)                                                           \
    }                                                                          \
    f32x4 sc[4] = {};                                                          \
    __builtin_amdgcn_s_setprio(1);                                             \
    _Pragma("unroll")                                                          \
    for (int kk = 0; kk < 2; ++kk) {                                           \
      const int colx = (kk * 32 + g * 8) ^ swz8;                               \
      _Pragma("unroll")                                                        \
      for (int tt = 0; tt < 4; ++tt) {                                         \
        bf16x8 kfrag = *reinterpret_cast<const bf16x8*>(&Ks[cur][tt * 16 + l15][colx]); \
        sc[tt] = __builtin_amdgcn_mfma_f32_16x16x32_bf16(kfrag, qa[kk], sc[tt], 0, 0, 0); \
      }                                                                        \
    }                                                                          \
    __builtin_amdgcn_s_setprio(0);                                             \
    const unsigned int rw[4] = {r##S##a.x, r##S##a.y, r##S##b.x, r##S##b.y};   \
    float pmax = -1e30f;                                                       \
    _Pragma("unroll")                                                          \
    for (int tt = 0; tt < 4; ++tt) {                                           \
      float v0 = sc[tt][0] + ldre(s_re2, rw[tt] & 0xFF);                       \
      float v1 = sc[tt][1] + ldre(s_re2, (rw[tt] >> 8) & 0xFF);                \
      float v2 = sc[tt][2] + ldre(s_re2, (rw[tt] >> 16) & 0xFF);               \
      float v3 = sc[tt][3] + ldre(s_re2, rw[tt] >> 24);                        \
      sc[tt][0] = v0; sc[tt][1] = v1; sc[tt][2] = v2; sc[tt][3] = v3;          \
      pmax = fmaxf(pmax, fmaxf(fmaxf(v0, v1), fmaxf(v2, v3)));                 \
    }                                                                          \
    if (!__all(pmax <= mofs + 8.0f)) {                                         \
      float pm = fmaxf(pmax, __shfl_xor(pmax, 16));                            \
      pm = fmaxf(pm, __shfl_xor(pm, 32));                                      \
      float mnew = fmaxf(mofs, pm);                                            \
      float alpha = exp2f(mofs - mnew);                                        \
      mofs = mnew;                                                             \
      everscaled = true;                                                       \
      float ar[4];                                                             \
      _Pragma("unroll")                                                        \
      for (int r = 0; r < 4; ++r) ar[r] = __shfl(alpha, 4 * g + r);            \
      _Pragma("unroll")                                                        \
      for (int r = 0; r < 4; ++r) l_acc[r] *= ar[r];                           \
      _Pragma("unroll")                                                        \
      for (int ht = 0; ht < 4; ++ht)                                           \
        _Pragma("unroll")                                                      \
        for (int r = 0; r < 4; ++r) ctx[ht][r] *= ar[r];                       \
    }                                                                          \
    unsigned int pw[8];                                                        \
    if (!everscaled) {                                                         \
      _Pragma("unroll")                                                        \
      for (int tt = 0; tt < 4; ++tt) {                                         \
        pw[2 * tt]     = cvtpk(exp2f(sc[tt][0]), exp2f(sc[tt][1]));            \
        pw[2 * tt + 1] = cvtpk(exp2f(sc[tt][2]), exp2f(sc[tt][3]));            \
      }                                                                        \
    } else {                                                                   \
      _Pragma("unroll")                                                        \
      for (int tt = 0; tt < 4; ++tt) {                                         \
        pw[2 * tt]     = cvtpk(exp2f(sc[tt][0] - mofs), exp2f(sc[tt][1] - mofs)); \
        pw[2 * tt + 1] = cvtpk(exp2f(sc[tt][2] - mofs), exp2f(sc[tt][3] - mofs)); \
      }                                                                        \
    }                                                                          \
    __builtin_amdgcn_s_setprio(1);                                             \
    _Pragma("unroll")                                                          \
    for (int kk = 0; kk < 2; ++kk) {                                           \
      u32x4 paw = {pw[4 * kk], pw[4 * kk + 1], pw[4 * kk + 2], pw[4 * kk + 3]};\
      bf16x8 pa = __builtin_bit_cast(bf16x8, paw);                             \
      bf16x8 mfr = *reinterpret_cast<const bf16x8*>(&s_emask[(tc) * 64 + kk * 32 + g * 8]); \
      l_acc = __builtin_amdgcn_mfma_f32_16x16x32_bf16(pa, mfr, l_acc, 0, 0, 0); \
      _Pragma("unroll")                                                        \
      for (int ht = 0; ht < 4; ++ht) {                                         \
        bf16x8 bfrag = *reinterpret_cast<const bf16x8*>(                       \
            &Vl[(size_t)(ht * 16) * NS + (tc) * 64 + kk * 32]);                \
        ctx[ht] = __builtin_amdgcn_mfma_f32_16x16x32_bf16(pa, bfrag, ctx[ht], 0, 0, 0); \
      }                                                                        \
    }                                                                          \
    __builtin_amdgcn_s_setprio(0);                                             \
    __syncthreads();                                                           \
  }

    for (int t = 0; t < 16; t += 2) {
        BODY(0, A, B, t, t + 1)
        BODY(1, B, A, t + 1, t + 2)
    }
#undef BODY
#undef LOADRM
#undef STAGE

    // epilogue: l_acc is already in ctx layout (row = q_local = 4g+r)
    float linv[4];
#pragma unroll
    for (int r = 0; r < 4; ++r) linv[r] = 1.0f / l_acc[r];
#pragma unroll
    for (int ht = 0; ht < 4; ++ht) {
        int hd = ht * 16 + l15;
#pragma unroll
        for (int r = 0; r < 4; ++r) {
            int qo = q0 + wave * 16 + 4 * g + r;
            out[((size_t)b * NS + qo) * ND + h * NHD + hd] = ctx[ht][r] * linv[r];
        }
    }
}

extern "C" void kernel_launch(void* const* d_in, const int* in_sizes, int n_in,
                              void* d_out, int out_size, void* d_ws, size_t ws_size,
                              hipStream_t stream) {
    const float* hs      = (const float*)d_in[0];
    const float* mask    = (const float*)d_in[1];
    const int*   rel     = (const int*)d_in[2];
    const float* Wq      = (const float*)d_in[3];
    const float* bq      = (const float*)d_in[4];
    const float* Wk      = (const float*)d_in[5];
    const float* bk      = (const float*)d_in[6];
    const float* Wv      = (const float*)d_in[7];
    const float* bv      = (const float*)d_in[8];
    const float* rel_emb = (const float*)d_in[9];
    float* out = (float*)d_out;

    char* ws = (char*)d_ws;
    unsigned short* q_bf  = (unsigned short*)(ws);                       // 16 MB
    unsigned short* k_bf  = (unsigned short*)(ws + ((size_t)16 << 20));  // 16 MB
    unsigned short* vt_bf = (unsigned short*)(ws + ((size_t)32 << 20));  // 16 MB
    unsigned short* hs_bf = (unsigned short*)(ws + ((size_t)48 << 20));  // 16 MB (freed after gemm)
    unsigned short* w_bf  = (unsigned short*)(ws + ((size_t)64 << 20));  // 6 MB
    unsigned char*  rel8  = (unsigned char*)(ws + ((size_t)48 << 20));   // 8.4 MB, reuses hs_bf

    const int nhs = NB * NS * ND;       // 8.4M
    const int nw  = ND * ND;            // 1M
    cvt_f32_bf16<<<nhs / 4 / 256, 256, 0, stream>>>(hs, hs_bf, nhs);
    cvt_w3<<<dim3(nw / 4 / 256, 3), 256, 0, stream>>>(Wq, Wk, Wv, w_bf);

    qkv_gemm<<<dim3((NB * NS) / 128, ND / 128, 3), 256, 0, stream>>>(
        hs_bf, w_bf, w_bf + (size_t)nw, w_bf + (size_t)2 * nw,
        bq, bk, bv, mask, q_bf, k_bf, vt_bf);

    // hs_bf is dead after qkv_gemm; pack rel into its space
    pack_rel8<<<(NB * NS * NS / 4) / 256, 256, 0, stream>>>(rel, (unsigned int*)rel8);

    flash_attn<<<1024, 512, 0, stream>>>(
        q_bf, k_bf, vt_bf, rel8, rel_emb, mask, out);
}

// Round 21
// 156.637 us; speedup vs baseline: 1.5333x; 1.5333x over previous
//
#include <hip/hip_runtime.h>

#define NB 8
#define NS 1024
#define ND 1024
#define NH 16
#define NHD 64

typedef __attribute__((ext_vector_type(8))) short bf16x8;
typedef __attribute__((ext_vector_type(4))) float f32x4;
typedef __attribute__((ext_vector_type(4))) unsigned int u32x4;

#define GLOAD_LDS16(g, l) __builtin_amdgcn_global_load_lds(                    \
    (const __attribute__((address_space(1))) void*)(g),                        \
    (__attribute__((address_space(3))) void*)(l), 16, 0, 0)

static __device__ __forceinline__ unsigned short f2bf(float f) {
    unsigned int u = __builtin_bit_cast(unsigned int, f);
    unsigned int r = u + 0x7fffu + ((u >> 16) & 1u);
    return (unsigned short)(r >> 16);
}

static __device__ __forceinline__ unsigned int cvtpk(float lo, float hi) {
    unsigned int r;
    asm("v_cvt_pk_bf16_f32 %0, %1, %2" : "=v"(r) : "v"(lo), "v"(hi));
    return r;
}

// load float from LDS table by BYTE offset (rel codes are pre-shifted <<2)
static __device__ __forceinline__ float ldre(const float* t, unsigned int byteoff) {
    return *reinterpret_cast<const float*>(reinterpret_cast<const char*>(t) + byteoff);
}

// ---------------- fp32 -> bf16 convert ----------------
__global__ void cvt_f32_bf16(const float* __restrict__ in, unsigned short* __restrict__ out, int n) {
    int i = (blockIdx.x * blockDim.x + threadIdx.x) * 4;
    if (i >= n) return;
    float4 v = *reinterpret_cast<const float4*>(in + i);
    ushort4 o;
    o.x = f2bf(v.x); o.y = f2bf(v.y); o.z = f2bf(v.z); o.w = f2bf(v.w);
    *reinterpret_cast<ushort4*>(out + i) = o;
}

// 3 weight matrices in one launch (grid.y selects source)
__global__ void cvt_w3(const float* __restrict__ Wq, const float* __restrict__ Wk,
                       const float* __restrict__ Wv, unsigned short* __restrict__ out) {
    const float* src = (blockIdx.y == 0) ? Wq : (blockIdx.y == 1) ? Wk : Wv;
    int i = (blockIdx.x * blockDim.x + threadIdx.x) * 4;
    float4 v = *reinterpret_cast<const float4*>(src + i);
    ushort4 o;
    o.x = f2bf(v.x); o.y = f2bf(v.y); o.z = f2bf(v.z); o.w = f2bf(v.w);
    *reinterpret_cast<ushort4*>(out + (size_t)blockIdx.y * (ND * ND) + i) = o;
}

// rel int32 -> packed int8, PRE-SHIFTED <<2 (byte value = LDS float byte-offset).
__global__ void pack_rel8(const int* __restrict__ rel, unsigned int* __restrict__ out) {
    int i = blockIdx.x * blockDim.x + threadIdx.x;
    int4 v = reinterpret_cast<const int4*>(rel)[i];
    out[i] = ((unsigned)v.x << 2) | ((unsigned)v.y << 10) |
             ((unsigned)v.z << 18) | ((unsigned)v.w << 26);
}

// ---------------- QKV projection GEMM (r17: LDS-bounce epilogue) ----------------
// Single-buffered 128x128 tile, BK=64, dim3(64,8,3) dispatch (best measured).
// Epilogue bounces each wave's 64x64 output tile through its own 8 KB LDS slice
// (As/Bs dead after the K-loop) and stores coalesced global_store_dwordx4 rows.
// z==0: Q pre-scaled by 0.125*log2(e). z==2: V pre-multiplied by exp2(mask*log2e).
__global__ __launch_bounds__(256) void qkv_gemm(
    const unsigned short* __restrict__ A,
    const unsigned short* __restrict__ Wq, const unsigned short* __restrict__ Wk,
    const unsigned short* __restrict__ Wv,
    const float* __restrict__ bq, const float* __restrict__ bk, const float* __restrict__ bv,
    const float* __restrict__ mask,
    unsigned short* __restrict__ Qo, unsigned short* __restrict__ Ko, unsigned short* __restrict__ Vo)
{
    const int z = blockIdx.z;
    const unsigned short* W = (z == 0) ? Wq : (z == 1) ? Wk : Wv;
    const float* bias = (z == 0) ? bq : (z == 1) ? bk : bv;
    const int m0 = blockIdx.x * 128;
    const int n0 = blockIdx.y * 128;
    const float LOG2E = 1.4426950408889634f;
    const float QSCL = 0.125f * 1.4426950408889634f;

    __shared__ unsigned short S[2][128][64];   // As=S[0], Bs=S[1]; 32 KB total

    const int tid = threadIdx.x;
    const int lane = tid & 63;
    const int wave = tid >> 6;
    const int wm = wave >> 1, wn = wave & 1;
    const int g = lane >> 4, l15 = lane & 15;

    f32x4 acc[4][4] = {};

    const int crow = lane >> 3;                    // row within chunk 0..7
    const int gcol = ((lane & 7) ^ crow) * 8;      // pre-swizzled source col (elems)
    const int kofs = g * 8;

    for (int kb = 0; kb < ND; kb += 64) {
#pragma unroll
        for (int cc = 0; cc < 4; ++cc) {
            int ch = wave * 4 + cc;                // 16 chunks each
            GLOAD_LDS16(&A[(size_t)(m0 + ch * 8 + crow) * ND + kb + gcol], &S[0][ch * 8][0]);
            GLOAD_LDS16(&W[(size_t)(n0 + ch * 8 + crow) * ND + kb + gcol], &S[1][ch * 8][0]);
        }
        __syncthreads();
#pragma unroll
        for (int kk = 0; kk < 2; ++kk) {
            const int colx = (kk * 32 + kofs) ^ ((lane & 7) * 8);
            bf16x8 af[4], bfr[4];
#pragma unroll
            for (int i = 0; i < 4; ++i) {
                af[i]  = *reinterpret_cast<const bf16x8*>(&S[0][wm * 64 + i * 16 + l15][colx]);
                bfr[i] = *reinterpret_cast<const bf16x8*>(&S[1][wn * 64 + i * 16 + l15][colx]);
            }
#pragma unroll
            for (int mi = 0; mi < 4; ++mi)
#pragma unroll
                for (int ni = 0; ni < 4; ++ni)
                    acc[mi][ni] = __builtin_amdgcn_mfma_f32_16x16x32_bf16(af[mi], bfr[ni], acc[mi][ni], 0, 0, 0);
        }
        __syncthreads();
    }

    // -------- LDS-bounce epilogue: per-wave 8 KB slice of S --------
    __syncthreads();   // all waves done reading S
    char* L = reinterpret_cast<char*>(&S[0][0][0]) + wave * 8192;
    const int rrow = lane >> 3, cb = lane & 7;

    if (z == 2) {
#pragma unroll
        for (int ni = 0; ni < 4; ++ni) {
            int n = n0 + wn * 64 + ni * 16 + l15;
            int nl = ni * 16 + l15;
            float bv_ = bias[n];
#pragma unroll
            for (int mi = 0; mi < 4; ++mi) {
                int m = m0 + wm * 64 + mi * 16 + g * 4;
                int b = m >> 10, s = m & 1023;
                float4 mv = *reinterpret_cast<const float4*>(&mask[(size_t)b * NS + s]);
                unsigned int lo = cvtpk((acc[mi][ni][0] + bv_) * exp2f(mv.x * LOG2E),
                                        (acc[mi][ni][1] + bv_) * exp2f(mv.y * LOG2E));
                unsigned int hi = cvtpk((acc[mi][ni][2] + bv_) * exp2f(mv.z * LOG2E),
                                        (acc[mi][ni][3] + bv_) * exp2f(mv.w * LOG2E));
                int ml = mi * 16 + g * 4;
                int off = nl * 128 + (((ml >> 3) ^ (nl & 7)) * 16) + (ml & 7) * 2;
                *reinterpret_cast<uint2*>(L + off) = make_uint2(lo, hi);
            }
        }
#pragma unroll
        for (int p = 0; p < 8; ++p) {
            int nl = p * 8 + rrow;
            u32x4 v = *reinterpret_cast<const u32x4*>(L + nl * 128 + ((cb ^ (nl & 7)) * 16));
            int n = n0 + wn * 64 + nl;
            int h = n >> 6, hd = n & 63;
            int m = m0 + wm * 64 + cb * 8;
            int b = m >> 10, s = m & 1023;
            *reinterpret_cast<u32x4*>(&Vo[(((size_t)b * NH + h) * NHD + hd) * NS + s]) = v;
        }
    } else {
        unsigned short* O = (z == 0) ? Qo : Ko;
#pragma unroll
        for (int ni = 0; ni < 4; ++ni) {
            int n = n0 + wn * 64 + ni * 16 + l15;
            int nl = ni * 16 + l15;
            float bv_ = bias[n];
            int c16 = nl >> 3, bin = (nl & 7) * 2;
#pragma unroll
            for (int mi = 0; mi < 4; ++mi) {
#pragma unroll
                for (int r = 0; r < 4; ++r) {
                    int ml = mi * 16 + g * 4 + r;
                    float v = acc[mi][ni][r] + bv_;
                    if (z == 0) v *= QSCL;
                    int off = ml * 128 + ((c16 ^ (ml & 7)) * 16) + bin;
                    *reinterpret_cast<unsigned short*>(L + off) = f2bf(v);
                }
            }
        }
#pragma unroll
        for (int p = 0; p < 8; ++p) {
            int ml = p * 8 + rrow;
            u32x4 v = *reinterpret_cast<const u32x4*>(L + ml * 128 + ((cb ^ (ml & 7)) * 16));
            int m = m0 + wm * 64 + ml;
            int b = m >> 10, s = m & 1023;
            int n = n0 + wn * 64 + cb * 8;
            int h = n >> 6, hd = n & 63;
            *reinterpret_cast<u32x4*>(&O[(((size_t)b * NH + h) * NS + s) * NHD + hd]) = v;
        }
    }
}

// ---------------- flash attention: XCD-clustered, K+V staged, P in regs ----------
// (round-13/17 structure — session best: 78.5 us. V staging retained: r20 showed
// direct-global V puts 8 synchronous VMEM loads on the PV critical path and
// collapses both pipes; r19 showed q-tiling x2 crosses the 64-VGPR cliff.)
__global__ __launch_bounds__(512) void flash_attn(
    const unsigned short* __restrict__ Q, const unsigned short* __restrict__ Kb,
    const unsigned short* __restrict__ Vt,
    const unsigned char* __restrict__ rel8, const float* __restrict__ rel_emb,
    const float* __restrict__ mask, float* __restrict__ out)
{
    const int id = blockIdx.x;
    const int b = id & 7;                 // XCD-clustered batch
    const int h = (id >> 3) & 15;
    const int q0 = (id >> 7) * 128;
    const int tid = threadIdx.x, lane = tid & 63, wave = tid >> 6;  // wave 0..7
    const int g = lane >> 4, l15 = lane & 15;

    __shared__ unsigned short Ks[2][64][64]; // [buf][perm-kv][hd], chunk-swizzled, 16 KB
    __shared__ unsigned short Vs[2][64][64]; // [buf][hd][kv], chunk-swizzled, 16 KB
    __shared__ unsigned short s_emask[NS];   // bf16 exp2(mask*log2e), 2 KB
    __shared__ float s_re2[8];               // rel_emb[.][h] * log2(e) - 4.0
    const float LOG2E = 1.4426950408889634f;
    if (tid < 7) s_re2[tid] = rel_emb[tid * NH + h] * LOG2E - 4.0f;

    const unsigned short* Qh = Q  + (((size_t)b * NH + h) * NS) * NHD;
    const unsigned short* Kh = Kb + (((size_t)b * NH + h) * NS) * NHD;
    const unsigned short* Vh = Vt + (((size_t)b * NH + h) * NHD) * NS;
    const int qg = q0 + wave * 16 + l15;                 // this lane's q-row
    const unsigned char* __restrict__ relrow = rel8 + (size_t)b * NS * NS + (size_t)qg * NS;
    const float* __restrict__ maskb = mask + (size_t)b * NS;

    bf16x8 qa[2];
    qa[0] = *reinterpret_cast<const bf16x8*>(&Qh[(size_t)qg * NHD + g * 8]);
    qa[1] = *reinterpret_cast<const bf16x8*>(&Qh[(size_t)qg * NHD + 32 + g * 8]);

    f32x4 ctx[4] = {};
    f32x4 l_acc = {};
    float mofs = 0.f;            // running-max minus the folded base (4.0)
    bool everscaled = false;     // sticky, wave-uniform

    const int crow = lane >> 3;
    const int gcol = ((lane & 7) ^ crow) * 8;
    const int swz8 = (lane & 7) * 8;          // == (l15&7)*8

    // K row-permutation for staging (loop-invariant per lane):
    const int rho = wave * 8 + crow;
    const int kvperm = ((rho >> 5) << 5) + (((rho >> 2) & 3) << 3)
                     + (((rho >> 4) & 1) << 2) + (rho & 3);

#define STAGE(buf, kv)                                                                          \
    {                                                                                           \
        GLOAD_LDS16(&Kh[(size_t)((kv) + kvperm) * NHD + gcol], &Ks[buf][wave * 8][0]);          \
        GLOAD_LDS16(&Vh[(size_t)(wave * 8 + crow) * NS + (kv) + gcol], &Vs[buf][wave * 8][0]);  \
    }

    // packed rel codes for tile t0: kv = 8g..8g+7 and 32+8g..+7 -> two 8B chunks
#define LOADRM(S, t0)                                                                \
    {                                                                                \
        r##S##a = *reinterpret_cast<const uint2*>(&relrow[(t0) * 64 + 8 * g]);       \
        r##S##b = *reinterpret_cast<const uint2*>(&relrow[(t0) * 64 + 32 + 8 * g]);  \
    }

    uint2 rAa, rAb, rBa, rBb;

    STAGE(0, 0)
    LOADRM(A, 0)
    s_emask[tid] = f2bf(exp2f(maskb[tid] * LOG2E));
    s_emask[tid + 512] = f2bf(exp2f(maskb[tid + 512] * LOG2E));
    __syncthreads();

#define BODY(cur, S, SN, tc, tn)                                               \
  {                                                                            \
    if ((tn) < 16) {                                                           \
      STAGE(cur ^ 1, (tn) * 64)                                                \
      LOADRM(SN, tn)                                                           \
    }                                                                          \
    f32x4 sc[4] = {};                                                          \
    __builtin_amdgcn_s_setprio(1);                                             \
    _Pragma("unroll")                                                          \
    for (int kk = 0; kk < 2; ++kk) {                                           \
      const int colx = (kk * 32 + g * 8) ^ swz8;                               \
      _Pragma("unroll")                                                        \
      for (int tt = 0; tt < 4; ++tt) {                                         \
        bf16x8 kfrag = *reinterpret_cast<const bf16x8*>(&Ks[cur][tt * 16 + l15][colx]); \
        sc[tt] = __builtin_amdgcn_mfma_f32_16x16x32_bf16(kfrag, qa[kk], sc[tt], 0, 0, 0); \
      }                                                                        \
    }                                                                          \
    __builtin_amdgcn_s_setprio(0);                                             \
    const unsigned int rw[4] = {r##S##a.x, r##S##a.y, r##S##b.x, r##S##b.y};   \
    float pmax = -1e30f;                                                       \
    _Pragma("unroll")                                                          \
    for (int tt = 0; tt < 4; ++tt) {                                           \
      float v0 = sc[tt][0] + ldre(s_re2, rw[tt] & 0xFF);                       \
      float v1 = sc[tt][1] + ldre(s_re2, (rw[tt] >> 8) & 0xFF);                \
      float v2 = sc[tt][2] + ldre(s_re2, (rw[tt] >> 16) & 0xFF);               \
      float v3 = sc[tt][3] + ldre(s_re2, rw[tt] >> 24);                        \
      sc[tt][0] = v0; sc[tt][1] = v1; sc[tt][2] = v2; sc[tt][3] = v3;          \
      pmax = fmaxf(pmax, fmaxf(fmaxf(v0, v1), fmaxf(v2, v3)));                 \
    }                                                                          \
    if (!__all(pmax <= mofs + 8.0f)) {                                         \
      float pm = fmaxf(pmax, __shfl_xor(pmax, 16));                            \
      pm = fmaxf(pm, __shfl_xor(pm, 32));                                      \
      float mnew = fmaxf(mofs, pm);                                            \
      float alpha = exp2f(mofs - mnew);                                        \
      mofs = mnew;                                                             \
      everscaled = true;                                                       \
      float ar[4];                                                             \
      _Pragma("unroll")                                                        \
      for (int r = 0; r < 4; ++r) ar[r] = __shfl(alpha, 4 * g + r);            \
      _Pragma("unroll")                                                        \
      for (int r = 0; r < 4; ++r) l_acc[r] *= ar[r];                           \
      _Pragma("unroll")                                                        \
      for (int ht = 0; ht < 4; ++ht)                                           \
        _Pragma("unroll")                                                      \
        for (int r = 0; r < 4; ++r) ctx[ht][r] *= ar[r];                       \
    }                                                                          \
    unsigned int pw[8];                                                        \
    if (!everscaled) {                                                         \
      _Pragma("unroll")                                                        \
      for (int tt = 0; tt < 4; ++tt) {                                         \
        pw[2 * tt]     = cvtpk(exp2f(sc[tt][0]), exp2f(sc[tt][1]));            \
        pw[2 * tt + 1] = cvtpk(exp2f(sc[tt][2]), exp2f(sc[tt][3]));            \
      }                                                                        \
    } else {                                                                   \
      _Pragma("unroll")                                                        \
      for (int tt = 0; tt < 4; ++tt) {                                         \
        pw[2 * tt]     = cvtpk(exp2f(sc[tt][0] - mofs), exp2f(sc[tt][1] - mofs)); \
        pw[2 * tt + 1] = cvtpk(exp2f(sc[tt][2] - mofs), exp2f(sc[tt][3] - mofs)); \
      }                                                                        \
    }                                                                          \
    __builtin_amdgcn_s_setprio(1);                                             \
    _Pragma("unroll")                                                          \
    for (int kk = 0; kk < 2; ++kk) {                                           \
      u32x4 paw = {pw[4 * kk], pw[4 * kk + 1], pw[4 * kk + 2], pw[4 * kk + 3]};\
      bf16x8 pa = __builtin_bit_cast(bf16x8, paw);                             \
      const int colx = (kk * 32 + g * 8) ^ swz8;                               \
      bf16x8 mfr = *reinterpret_cast<const bf16x8*>(&s_emask[(tc) * 64 + kk * 32 + g * 8]); \
      l_acc = __builtin_amdgcn_mfma_f32_16x16x32_bf16(pa, mfr, l_acc, 0, 0, 0); \
      _Pragma("unroll")                                                        \
      for (int ht = 0; ht < 4; ++ht) {                                         \
        bf16x8 bfrag = *reinterpret_cast<const bf16x8*>(&Vs[cur][ht * 16 + l15][colx]); \
        ctx[ht] = __builtin_amdgcn_mfma_f32_16x16x32_bf16(pa, bfrag, ctx[ht], 0, 0, 0); \
      }                                                                        \
    }                                                                          \
    __builtin_amdgcn_s_setprio(0);                                             \
    __syncthreads();                                                           \
  }

    for (int t = 0; t < 16; t += 2) {
        BODY(0, A, B, t, t + 1)
        BODY(1, B, A, t + 1, t + 2)
    }
#undef BODY
#undef LOADRM
#undef STAGE

    // epilogue: l_acc is already in ctx layout (row = q_local = 4g+r)
    float linv[4];
#pragma unroll
    for (int r = 0; r < 4; ++r) linv[r] = 1.0f / l_acc[r];
#pragma unroll
    for (int ht = 0; ht < 4; ++ht) {
        int hd = ht * 16 + l15;
#pragma unroll
        for (int r = 0; r < 4; ++r) {
            int qo = q0 + wave * 16 + 4 * g + r;
            out[((size_t)b * NS + qo) * ND + h * NHD + hd] = ctx[ht][r] * linv[r];
        }
    }
}

extern "C" void kernel_launch(void* const* d_in, const int* in_sizes, int n_in,
                              void* d_out, int out_size, void* d_ws, size_t ws_size,
                              hipStream_t stream) {
    const float* hs      = (const float*)d_in[0];
    const float* mask    = (const float*)d_in[1];
    const int*   rel     = (const int*)d_in[2];
    const float* Wq      = (const float*)d_in[3];
    const float* bq      = (const float*)d_in[4];
    const float* Wk      = (const float*)d_in[5];
    const float* bk      = (const float*)d_in[6];
    const float* Wv      = (const float*)d_in[7];
    const float* bv      = (const float*)d_in[8];
    const float* rel_emb = (const float*)d_in[9];
    float* out = (float*)d_out;

    char* ws = (char*)d_ws;
    unsigned short* q_bf  = (unsigned short*)(ws);                       // 16 MB
    unsigned short* k_bf  = (unsigned short*)(ws + ((size_t)16 << 20));  // 16 MB
    unsigned short* vt_bf = (unsigned short*)(ws + ((size_t)32 << 20));  // 16 MB
    unsigned short* hs_bf = (unsigned short*)(ws + ((size_t)48 << 20));  // 16 MB (freed after gemm)
    unsigned short* w_bf  = (unsigned short*)(ws + ((size_t)64 << 20));  // 6 MB
    unsigned char*  rel8  = (unsigned char*)(ws + ((size_t)48 << 20));   // 8.4 MB, reuses hs_bf

    const int nhs = NB * NS * ND;       // 8.4M
    const int nw  = ND * ND;            // 1M
    cvt_f32_bf16<<<nhs / 4 / 256, 256, 0, stream>>>(hs, hs_bf, nhs);
    cvt_w3<<<dim3(nw / 4 / 256, 3), 256, 0, stream>>>(Wq, Wk, Wv, w_bf);

    qkv_gemm<<<dim3((NB * NS) / 128, ND / 128, 3), 256, 0, stream>>>(
        hs_bf, w_bf, w_bf + (size_t)nw, w_bf + (size_t)2 * nw,
        bq, bk, bv, mask, q_bf, k_bf, vt_bf);

    // hs_bf is dead after qkv_gemm; pack rel into its space
    pack_rel8<<<(NB * NS * NS / 4) / 256, 256, 0, stream>>>(rel, (unsigned int*)rel8);

    flash_attn<<<1024, 512, 0, stream>>>(
        q_bf, k_bf, vt_bf, rel8, rel_emb, mask, out);
}

// Round 22
// 155.521 us; speedup vs baseline: 1.5443x; 1.0072x over previous
//
#include <hip/hip_runtime.h>

#define NB 8
#define NS 1024
#define ND 1024
#define NH 16
#define NHD 64

typedef __attribute__((ext_vector_type(8))) short bf16x8;
typedef __attribute__((ext_vector_type(4))) float f32x4;
typedef __attribute__((ext_vector_type(4))) unsigned int u32x4;

#define GLOAD_LDS16(g, l) __builtin_amdgcn_global_load_lds(                    \
    (const __attribute__((address_space(1))) void*)(g),                        \
    (__attribute__((address_space(3))) void*)(l), 16, 0, 0)

static __device__ __forceinline__ unsigned short f2bf(float f) {
    unsigned int u = __builtin_bit_cast(unsigned int, f);
    unsigned int r = u + 0x7fffu + ((u >> 16) & 1u);
    return (unsigned short)(r >> 16);
}

static __device__ __forceinline__ unsigned int cvtpk(float lo, float hi) {
    unsigned int r;
    asm("v_cvt_pk_bf16_f32 %0, %1, %2" : "=v"(r) : "v"(lo), "v"(hi));
    return r;
}

// load float from LDS table by BYTE offset (rel codes are pre-shifted <<2)
static __device__ __forceinline__ float ldre(const float* t, unsigned int byteoff) {
    return *reinterpret_cast<const float*>(reinterpret_cast<const char*>(t) + byteoff);
}

// ---------------- fused fp32 -> bf16 convert: hs + Wq + Wk + Wv in ONE launch ----
// quad-indexed flat grid: [0, 2097152) -> hs, then 3 x 262144 quads for weights.
__global__ void cvt_all(const float* __restrict__ hs,
                        const float* __restrict__ Wq, const float* __restrict__ Wk,
                        const float* __restrict__ Wv,
                        unsigned short* __restrict__ hs_bf, unsigned short* __restrict__ w_bf) {
    const int i = blockIdx.x * blockDim.x + threadIdx.x;     // quad index
    const int nq_hs = (NB * NS * ND) / 4;                    // 2,097,152
    const int nq_w  = (ND * ND) / 4;                         // 262,144 (= 2^18)
    const float* src;
    unsigned short* dst;
    int j;
    if (i < nq_hs) {
        src = hs; dst = hs_bf; j = i;
    } else {
        int k = i - nq_hs;
        int w = k >> 18;                                     // /nq_w
        j = k & (nq_w - 1);
        src = (w == 0) ? Wq : (w == 1) ? Wk : Wv;
        dst = w_bf + (size_t)w * (ND * ND);
    }
    float4 v = *reinterpret_cast<const float4*>(src + (size_t)j * 4);
    ushort4 o;
    o.x = f2bf(v.x); o.y = f2bf(v.y); o.z = f2bf(v.z); o.w = f2bf(v.w);
    *reinterpret_cast<ushort4*>(dst + (size_t)j * 4) = o;
}

// rel int32 -> packed int8, PRE-SHIFTED <<2 (byte value = LDS float byte-offset).
__global__ void pack_rel8(const int* __restrict__ rel, unsigned int* __restrict__ out) {
    int i = blockIdx.x * blockDim.x + threadIdx.x;
    int4 v = reinterpret_cast<const int4*>(rel)[i];
    out[i] = ((unsigned)v.x << 2) | ((unsigned)v.y << 10) |
             ((unsigned)v.z << 18) | ((unsigned)v.w << 26);
}

// ---------------- QKV projection GEMM (r17: LDS-bounce epilogue) ----------------
// Single-buffered 128x128 tile, BK=64, dim3(64,8,3) dispatch (best measured).
// Epilogue bounces each wave's 64x64 output tile through its own 8 KB LDS slice
// (As/Bs dead after the K-loop) and stores coalesced global_store_dwordx4 rows.
// z==0: Q pre-scaled by 0.125*log2(e). z==2: V pre-multiplied by exp2(mask*log2e).
__global__ __launch_bounds__(256) void qkv_gemm(
    const unsigned short* __restrict__ A,
    const unsigned short* __restrict__ Wq, const unsigned short* __restrict__ Wk,
    const unsigned short* __restrict__ Wv,
    const float* __restrict__ bq, const float* __restrict__ bk, const float* __restrict__ bv,
    const float* __restrict__ mask,
    unsigned short* __restrict__ Qo, unsigned short* __restrict__ Ko, unsigned short* __restrict__ Vo)
{
    const int z = blockIdx.z;
    const unsigned short* W = (z == 0) ? Wq : (z == 1) ? Wk : Wv;
    const float* bias = (z == 0) ? bq : (z == 1) ? bk : bv;
    const int m0 = blockIdx.x * 128;
    const int n0 = blockIdx.y * 128;
    const float LOG2E = 1.4426950408889634f;
    const float QSCL = 0.125f * 1.4426950408889634f;

    __shared__ unsigned short S[2][128][64];   // As=S[0], Bs=S[1]; 32 KB total

    const int tid = threadIdx.x;
    const int lane = tid & 63;
    const int wave = tid >> 6;
    const int wm = wave >> 1, wn = wave & 1;
    const int g = lane >> 4, l15 = lane & 15;

    f32x4 acc[4][4] = {};

    const int crow = lane >> 3;                    // row within chunk 0..7
    const int gcol = ((lane & 7) ^ crow) * 8;      // pre-swizzled source col (elems)
    const int kofs = g * 8;

    for (int kb = 0; kb < ND; kb += 64) {
#pragma unroll
        for (int cc = 0; cc < 4; ++cc) {
            int ch = wave * 4 + cc;                // 16 chunks each
            GLOAD_LDS16(&A[(size_t)(m0 + ch * 8 + crow) * ND + kb + gcol], &S[0][ch * 8][0]);
            GLOAD_LDS16(&W[(size_t)(n0 + ch * 8 + crow) * ND + kb + gcol], &S[1][ch * 8][0]);
        }
        __syncthreads();
#pragma unroll
        for (int kk = 0; kk < 2; ++kk) {
            const int colx = (kk * 32 + kofs) ^ ((lane & 7) * 8);
            bf16x8 af[4], bfr[4];
#pragma unroll
            for (int i = 0; i < 4; ++i) {
                af[i]  = *reinterpret_cast<const bf16x8*>(&S[0][wm * 64 + i * 16 + l15][colx]);
                bfr[i] = *reinterpret_cast<const bf16x8*>(&S[1][wn * 64 + i * 16 + l15][colx]);
            }
#pragma unroll
            for (int mi = 0; mi < 4; ++mi)
#pragma unroll
                for (int ni = 0; ni < 4; ++ni)
                    acc[mi][ni] = __builtin_amdgcn_mfma_f32_16x16x32_bf16(af[mi], bfr[ni], acc[mi][ni], 0, 0, 0);
        }
        __syncthreads();
    }

    // -------- LDS-bounce epilogue: per-wave 8 KB slice of S --------
    __syncthreads();   // all waves done reading S
    char* L = reinterpret_cast<char*>(&S[0][0][0]) + wave * 8192;
    const int rrow = lane >> 3, cb = lane & 7;

    if (z == 2) {
#pragma unroll
        for (int ni = 0; ni < 4; ++ni) {
            int n = n0 + wn * 64 + ni * 16 + l15;
            int nl = ni * 16 + l15;
            float bv_ = bias[n];
#pragma unroll
            for (int mi = 0; mi < 4; ++mi) {
                int m = m0 + wm * 64 + mi * 16 + g * 4;
                int b = m >> 10, s = m & 1023;
                float4 mv = *reinterpret_cast<const float4*>(&mask[(size_t)b * NS + s]);
                unsigned int lo = cvtpk((acc[mi][ni][0] + bv_) * exp2f(mv.x * LOG2E),
                                        (acc[mi][ni][1] + bv_) * exp2f(mv.y * LOG2E));
                unsigned int hi = cvtpk((acc[mi][ni][2] + bv_) * exp2f(mv.z * LOG2E),
                                        (acc[mi][ni][3] + bv_) * exp2f(mv.w * LOG2E));
                int ml = mi * 16 + g * 4;
                int off = nl * 128 + (((ml >> 3) ^ (nl & 7)) * 16) + (ml & 7) * 2;
                *reinterpret_cast<uint2*>(L + off) = make_uint2(lo, hi);
            }
        }
#pragma unroll
        for (int p = 0; p < 8; ++p) {
            int nl = p * 8 + rrow;
            u32x4 v = *reinterpret_cast<const u32x4*>(L + nl * 128 + ((cb ^ (nl & 7)) * 16));
            int n = n0 + wn * 64 + nl;
            int h = n >> 6, hd = n & 63;
            int m = m0 + wm * 64 + cb * 8;
            int b = m >> 10, s = m & 1023;
            *reinterpret_cast<u32x4*>(&Vo[(((size_t)b * NH + h) * NHD + hd) * NS + s]) = v;
        }
    } else {
        unsigned short* O = (z == 0) ? Qo : Ko;
#pragma unroll
        for (int ni = 0; ni < 4; ++ni) {
            int n = n0 + wn * 64 + ni * 16 + l15;
            int nl = ni * 16 + l15;
            float bv_ = bias[n];
            int c16 = nl >> 3, bin = (nl & 7) * 2;
#pragma unroll
            for (int mi = 0; mi < 4; ++mi) {
#pragma unroll
                for (int r = 0; r < 4; ++r) {
                    int ml = mi * 16 + g * 4 + r;
                    float v = acc[mi][ni][r] + bv_;
                    if (z == 0) v *= QSCL;
                    int off = ml * 128 + ((c16 ^ (ml & 7)) * 16) + bin;
                    *reinterpret_cast<unsigned short*>(L + off) = f2bf(v);
                }
            }
        }
#pragma unroll
        for (int p = 0; p < 8; ++p) {
            int ml = p * 8 + rrow;
            u32x4 v = *reinterpret_cast<const u32x4*>(L + ml * 128 + ((cb ^ (ml & 7)) * 16));
            int m = m0 + wm * 64 + ml;
            int b = m >> 10, s = m & 1023;
            int n = n0 + wn * 64 + cb * 8;
            int h = n >> 6, hd = n & 63;
            *reinterpret_cast<u32x4*>(&O[(((size_t)b * NH + h) * NS + s) * NHD + hd]) = v;
        }
    }
}

// ---------------- flash attention: XCD-clustered, K+V staged, P in regs ----------
// (round-13/17 structure — session best: 78.3 us. V staging retained: r20 showed
// direct-global V puts 8 synchronous VMEM loads on the PV critical path and
// collapses both pipes; r19 showed q-tiling x2 crosses the 64-VGPR cliff.)
__global__ __launch_bounds__(512) void flash_attn(
    const unsigned short* __restrict__ Q, const unsigned short* __restrict__ Kb,
    const unsigned short* __restrict__ Vt,
    const unsigned char* __restrict__ rel8, const float* __restrict__ rel_emb,
    const float* __restrict__ mask, float* __restrict__ out)
{
    const int id = blockIdx.x;
    const int b = id & 7;                 // XCD-clustered batch
    const int h = (id >> 3) & 15;
    const int q0 = (id >> 7) * 128;
    const int tid = threadIdx.x, lane = tid & 63, wave = tid >> 6;  // wave 0..7
    const int g = lane >> 4, l15 = lane & 15;

    __shared__ unsigned short Ks[2][64][64]; // [buf][perm-kv][hd], chunk-swizzled, 16 KB
    __shared__ unsigned short Vs[2][64][64]; // [buf][hd][kv], chunk-swizzled, 16 KB
    __shared__ unsigned short s_emask[NS];   // bf16 exp2(mask*log2e), 2 KB
    __shared__ float s_re2[8];               // rel_emb[.][h] * log2(e) - 4.0
    const float LOG2E = 1.4426950408889634f;
    if (tid < 7) s_re2[tid] = rel_emb[tid * NH + h] * LOG2E - 4.0f;

    const unsigned short* Qh = Q  + (((size_t)b * NH + h) * NS) * NHD;
    const unsigned short* Kh = Kb + (((size_t)b * NH + h) * NS) * NHD;
    const unsigned short* Vh = Vt + (((size_t)b * NH + h) * NHD) * NS;
    const int qg = q0 + wave * 16 + l15;                 // this lane's q-row
    const unsigned char* __restrict__ relrow = rel8 + (size_t)b * NS * NS + (size_t)qg * NS;
    const float* __restrict__ maskb = mask + (size_t)b * NS;

    bf16x8 qa[2];
    qa[0] = *reinterpret_cast<const bf16x8*>(&Qh[(size_t)qg * NHD + g * 8]);
    qa[1] = *reinterpret_cast<const bf16x8*>(&Qh[(size_t)qg * NHD + 32 + g * 8]);

    f32x4 ctx[4] = {};
    f32x4 l_acc = {};
    float mofs = 0.f;            // running-max minus the folded base (4.0)
    bool everscaled = false;     // sticky, wave-uniform

    const int crow = lane >> 3;
    const int gcol = ((lane & 7) ^ crow) * 8;
    const int swz8 = (lane & 7) * 8;          // == (l15&7)*8

    // K row-permutation for staging (loop-invariant per lane):
    const int rho = wave * 8 + crow;
    const int kvperm = ((rho >> 5) << 5) + (((rho >> 2) & 3) << 3)
                     + (((rho >> 4) & 1) << 2) + (rho & 3);

#define STAGE(buf, kv)                                                                          \
    {                                                                                           \
        GLOAD_LDS16(&Kh[(size_t)((kv) + kvperm) * NHD + gcol], &Ks[buf][wave * 8][0]);          \
        GLOAD_LDS16(&Vh[(size_t)(wave * 8 + crow) * NS + (kv) + gcol], &Vs[buf][wave * 8][0]);  \
    }

    // packed rel codes for tile t0: kv = 8g..8g+7 and 32+8g..+7 -> two 8B chunks
#define LOADRM(S, t0)                                                                \
    {                                                                                \
        r##S##a = *reinterpret_cast<const uint2*>(&relrow[(t0) * 64 + 8 * g]);       \
        r##S##b = *reinterpret_cast<const uint2*>(&relrow[(t0) * 64 + 32 + 8 * g]);  \
    }

    uint2 rAa, rAb, rBa, rBb;

    STAGE(0, 0)
    LOADRM(A, 0)
    s_emask[tid] = f2bf(exp2f(maskb[tid] * LOG2E));
    s_emask[tid + 512] = f2bf(exp2f(maskb[tid + 512] * LOG2E));
    __syncthreads();

#define BODY(cur, S, SN, tc, tn)                                               \
  {                                                                            \
    if ((tn) < 16) {                                                           \
      STAGE(cur ^ 1, (tn) * 64)                                                \
      LOADRM(SN, tn)                                                           \
    }                                                                          \
    f32x4 sc[4] = {};                                                          \
    __builtin_amdgcn_s_setprio(1);                                             \
    _Pragma("unroll")                                                          \
    for (int kk = 0; kk < 2; ++kk) {                                           \
      const int colx = (kk * 32 + g * 8) ^ swz8;                               \
      _Pragma("unroll")                                                        \
      for (int tt = 0; tt < 4; ++tt) {                                         \
        bf16x8 kfrag = *reinterpret_cast<const bf16x8*>(&Ks[cur][tt * 16 + l15][colx]); \
        sc[tt] = __builtin_amdgcn_mfma_f32_16x16x32_bf16(kfrag, qa[kk], sc[tt], 0, 0, 0); \
      }                                                                        \
    }                                                                          \
    __builtin_amdgcn_s_setprio(0);                                             \
    const unsigned int rw[4] = {r##S##a.x, r##S##a.y, r##S##b.x, r##S##b.y};   \
    float pmax = -1e30f;                                                       \
    _Pragma("unroll")                                                          \
    for (int tt = 0; tt < 4; ++tt) {                                           \
      float v0 = sc[tt][0] + ldre(s_re2, rw[tt] & 0xFF);                       \
      float v1 = sc[tt][1] + ldre(s_re2, (rw[tt] >> 8) & 0xFF);                \
      float v2 = sc[tt][2] + ldre(s_re2, (rw[tt] >> 16) & 0xFF);               \
      float v3 = sc[tt][3] + ldre(s_re2, rw[tt] >> 24);                        \
      sc[tt][0] = v0; sc[tt][1] = v1; sc[tt][2] = v2; sc[tt][3] = v3;          \
      pmax = fmaxf(pmax, fmaxf(fmaxf(v0, v1), fmaxf(v2, v3)));                 \
    }                                                                          \
    if (!__all(pmax <= mofs + 8.0f)) {                                         \
      float pm = fmaxf(pmax, __shfl_xor(pmax, 16));                            \
      pm = fmaxf(pm, __shfl_xor(pm, 32));                                      \
      float mnew = fmaxf(mofs, pm);                                            \
      float alpha = exp2f(mofs - mnew);                                        \
      mofs = mnew;                                                             \
      everscaled = true;                                                       \
      float ar[4];                                                             \
      _Pragma("unroll")                                                        \
      for (int r = 0; r < 4; ++r) ar[r] = __shfl(alpha, 4 * g + r);            \
      _Pragma("unroll")                                                        \
      for (int r = 0; r < 4; ++r) l_acc[r] *= ar[r];                           \
      _Pragma("unroll")                                                        \
      for (int ht = 0; ht < 4; ++ht)                                           \
        _Pragma("unroll")                                                      \
        for (int r = 0; r < 4; ++r) ctx[ht][r] *= ar[r];                       \
    }                                                                          \
    unsigned int pw[8];                                                        \
    if (!everscaled) {                                                         \
      _Pragma("unroll")                                                        \
      for (int tt = 0; tt < 4; ++tt) {                                         \
        pw[2 * tt]     = cvtpk(exp2f(sc[tt][0]), exp2f(sc[tt][1]));            \
        pw[2 * tt + 1] = cvtpk(exp2f(sc[tt][2]), exp2f(sc[tt][3]));            \
      }                                                                        \
    } else {                                                                   \
      _Pragma("unroll")                                                        \
      for (int tt = 0; tt < 4; ++tt) {                                         \
        pw[2 * tt]     = cvtpk(exp2f(sc[tt][0] - mofs), exp2f(sc[tt][1] - mofs)); \
        pw[2 * tt + 1] = cvtpk(exp2f(sc[tt][2] - mofs), exp2f(sc[tt][3] - mofs)); \
      }                                                                        \
    }                                                                          \
    __builtin_amdgcn_s_setprio(1);                                             \
    _Pragma("unroll")                                                          \
    for (int kk = 0; kk < 2; ++kk) {                                           \
      u32x4 paw = {pw[4 * kk], pw[4 * kk + 1], pw[4 * kk + 2], pw[4 * kk + 3]};\
      bf16x8 pa = __builtin_bit_cast(bf16x8, paw);                             \
      const int colx = (kk * 32 + g * 8) ^ swz8;                               \
      bf16x8 mfr = *reinterpret_cast<const bf16x8*>(&s_emask[(tc) * 64 + kk * 32 + g * 8]); \
      l_acc = __builtin_amdgcn_mfma_f32_16x16x32_bf16(pa, mfr, l_acc, 0, 0, 0); \
      _Pragma("unroll")                                                        \
      for (int ht = 0; ht < 4; ++ht) {                                         \
        bf16x8 bfrag = *reinterpret_cast<const bf16x8*>(&Vs[cur][ht * 16 + l15][colx]); \
        ctx[ht] = __builtin_amdgcn_mfma_f32_16x16x32_bf16(pa, bfrag, ctx[ht], 0, 0, 0); \
      }                                                                        \
    }                                                                          \
    __builtin_amdgcn_s_setprio(0);                                             \
    __syncthreads();                                                           \
  }

    for (int t = 0; t < 16; t += 2) {
        BODY(0, A, B, t, t + 1)
        BODY(1, B, A, t + 1, t + 2)
    }
#undef BODY
#undef LOADRM
#undef STAGE

    // epilogue: l_acc is already in ctx layout (row = q_local = 4g+r)
    float linv[4];
#pragma unroll
    for (int r = 0; r < 4; ++r) linv[r] = 1.0f / l_acc[r];
#pragma unroll
    for (int ht = 0; ht < 4; ++ht) {
        int hd = ht * 16 + l15;
#pragma unroll
        for (int r = 0; r < 4; ++r) {
            int qo = q0 + wave * 16 + 4 * g + r;
            out[((size_t)b * NS + qo) * ND + h * NHD + hd] = ctx[ht][r] * linv[r];
        }
    }
}

extern "C" void kernel_launch(void* const* d_in, const int* in_sizes, int n_in,
                              void* d_out, int out_size, void* d_ws, size_t ws_size,
                              hipStream_t stream) {
    const float* hs      = (const float*)d_in[0];
    const float* mask    = (const float*)d_in[1];
    const int*   rel     = (const int*)d_in[2];
    const float* Wq      = (const float*)d_in[3];
    const float* bq      = (const float*)d_in[4];
    const float* Wk      = (const float*)d_in[5];
    const float* bk      = (const float*)d_in[6];
    const float* Wv      = (const float*)d_in[7];
    const float* bv      = (const float*)d_in[8];
    const float* rel_emb = (const float*)d_in[9];
    float* out = (float*)d_out;

    char* ws = (char*)d_ws;
    unsigned short* q_bf  = (unsigned short*)(ws);                       // 16 MB
    unsigned short* k_bf  = (unsigned short*)(ws + ((size_t)16 << 20));  // 16 MB
    unsigned short* vt_bf = (unsigned short*)(ws + ((size_t)32 << 20));  // 16 MB
    unsigned short* hs_bf = (unsigned short*)(ws + ((size_t)48 << 20));  // 16 MB (freed after gemm)
    unsigned short* w_bf  = (unsigned short*)(ws + ((size_t)64 << 20));  // 6 MB
    unsigned char*  rel8  = (unsigned char*)(ws + ((size_t)48 << 20));   // 8.4 MB, reuses hs_bf

    const int nhs = NB * NS * ND;       // 8.4M
    const int nw  = ND * ND;            // 1M
    // fused convert: hs (2,097,152 quads) + 3 weights (3 x 262,144 quads) = 11264 blocks
    cvt_all<<<(nhs / 4 + 3 * (nw / 4)) / 256, 256, 0, stream>>>(
        hs, Wq, Wk, Wv, hs_bf, w_bf);

    qkv_gemm<<<dim3((NB * NS) / 128, ND / 128, 3), 256, 0, stream>>>(
        hs_bf, w_bf, w_bf + (size_t)nw, w_bf + (size_t)2 * nw,
        bq, bk, bv, mask, q_bf, k_bf, vt_bf);

    // hs_bf is dead after qkv_gemm; pack rel into its space
    pack_rel8<<<(NB * NS * NS / 4) / 256, 256, 0, stream>>>(rel, (unsigned int*)rel8);

    flash_attn<<<1024, 512, 0, stream>>>(
        q_bf, k_bf, vt_bf, rel8, rel_emb, mask, out);
}